// Round 5
// baseline (410.997 us; speedup 1.0000x reference)
//
#include <hip/hip_runtime.h>
#include <hip/hip_bf16.h>
#include <math.h>

#define B_SZ 16
#define D_CH 512
#define U_LEN 2048
#define R_LEN 512
#define T_LEN 2560
#define KS 31
#define CS 30

typedef __attribute__((ext_vector_type(8))) short short8;
typedef __attribute__((ext_vector_type(4))) float floatx4;

__device__ __forceinline__ float bf2f(ushort u) {
    unsigned v = (unsigned)u << 16;
    float f; __builtin_memcpy(&f, &v, 4); return f;
}
__device__ __forceinline__ ushort f2bf(float f) {
    unsigned v; __builtin_memcpy(&v, &f, 4);
    v += 0x7fff + ((v >> 16) & 1);
    return (ushort)(v >> 16);
}
// packed fp32x2 -> bf16x2 (v_cvt_pk_bf16_f32 on gfx950)
__device__ __forceinline__ unsigned pk2bf(float x, float y) {
    __hip_bfloat162 h = __float22bfloat162_rn(make_float2(x, y));
    unsigned u; __builtin_memcpy(&u, &h, 4); return u;
}
__device__ __forceinline__ float sigmoidf_(float x) { return 1.0f / (1.0f + __expf(-x)); }

__device__ __forceinline__ void gld16(const void* g, void* l) {
    __builtin_amdgcn_global_load_lds((const __attribute__((address_space(1))) void*)g,
                                     (__attribute__((address_space(3))) void*)l, 16, 0, 0);
}

// ---- small conversion: weights -> bf16, cache -> (CS,B,D) bf16 ----
__global__ __launch_bounds__(256) void k_conv_small(
    const float* __restrict__ cache, const float* __restrict__ w1, const float* __restrict__ w2,
    ushort* __restrict__ w1b, ushort* __restrict__ w2b, ushort* __restrict__ xc)
{
    int blk = blockIdx.x;
    if (blk < 768) {
        int t = blk * 256 + threadIdx.x;  // float4 index, 196608 total
        const float* src; ushort* dst;
        if (t < 131072) { src = w1; dst = w1b; }
        else            { t -= 131072; src = w2; dst = w2b; }
        float4 v = ((const float4*)src)[t];
        ushort4 u4; u4.x = f2bf(v.x); u4.y = f2bf(v.y); u4.z = f2bf(v.z); u4.w = f2bf(v.w);
        ((ushort4*)dst)[t] = u4;
    } else {
        int o = (blk - 768) * 256 + threadIdx.x;  // 245760 total, output-indexed
        int d = o & 511, p = o >> 13, b = (o >> 9) & 15;
        xc[o] = f2bf(cache[((size_t)b * D_CH + d) * CS + p]);
    }
}

// ---- K1: dbuf MFMA GEMM with fused fp32->bf16 A-staging + GLU -> y bf16 ----
// A (utt/rc fp32) loaded to regs, cvt_pk, ds_write; B (w1b bf16) via gld16.
// XCD swizzle: 8 n-blocks sharing an A-tile land on one XCD.
// NO min-waves cap (R3: capping spills 128-VGPR accumulators -> 1.5GB scratch).
__global__ __launch_bounds__(256) void k1_mfma(
    const float* __restrict__ utt, const float* __restrict__ rc,
    const ushort* __restrict__ w1b, const float* __restrict__ b1, ushort* __restrict__ y)
{
    __shared__ __attribute__((aligned(16))) ushort sA[2][256 * 32];
    __shared__ __attribute__((aligned(16))) ushort sBa[2][64 * 32];
    __shared__ __attribute__((aligned(16))) ushort sBg[2][64 * 32];
    const int tid = threadIdx.x;
    const int w = tid >> 6, lane = tid & 63;
    const int f = blockIdx.x;
    const int xcd = f & 7, nn = (f >> 3) & 7, qh = f >> 6;
    const int q0 = (qh * 8 + xcd) * 256;
    const int n0 = nn * 64;
    const int col = lane & 15, quad = lane >> 4;

    const float* asrc = (q0 < 8192) ? rc + ((size_t)q0 << 9)
                                    : utt + (((size_t)(q0 - 8192)) << 9);
    const int lrow = lane >> 3;          // 0..7
    const int lk4  = (lane & 7) * 4;     // float offset in 32-k chunk

    floatx4 acc_a[4][4], acc_g[4][4];
    #pragma unroll
    for (int i = 0; i < 4; ++i)
        #pragma unroll
        for (int j = 0; j < 4; ++j) { acc_a[i][j] = 0.f; acc_g[i][j] = 0.f; }

    const int sBs = w * 64 + lane;
    const int sBr = sBs >> 2, sBh = sBs & 3;

    float4 apf[8];

#define LOADA1(kc) do { \
        _Pragma("unroll") \
        for (int ii = 0; ii < 8; ++ii) \
            apf[ii] = *(const float4*)(asrc + (((size_t)(w * 64 + lrow + 8 * ii)) << 9) + (kc) + lk4); \
    } while (0)
#define STAGEB1(kc, buf) do { \
        gld16(w1b + (((size_t)(n0 + sBr)) << 9) + (kc) + sBh * 8, &sBa[buf][w * 512]); \
        gld16(w1b + (((size_t)(512 + n0 + sBr)) << 9) + (kc) + sBh * 8, &sBg[buf][w * 512]); \
    } while (0)
#define CVTW1(buf) do { \
        _Pragma("unroll") \
        for (int ii = 0; ii < 8; ++ii) { \
            int2 pv; pv.x = pk2bf(apf[ii].x, apf[ii].y); pv.y = pk2bf(apf[ii].z, apf[ii].w); \
            *(int2*)&sA[buf][(w * 64 + lrow + 8 * ii) * 32 + lk4] = pv; \
        } \
    } while (0)

    LOADA1(0);
    STAGEB1(0, 0);
    CVTW1(0);
    #pragma unroll
    for (int kc = 0; kc < 512; kc += 32) {
        const int buf = (kc >> 5) & 1;
        __syncthreads();
        if (kc + 32 < 512) { LOADA1(kc + 32); STAGEB1(kc + 32, buf ^ 1); }

        short8 af[4], ba[4], bg[4];
        #pragma unroll
        for (int i = 0; i < 4; ++i)
            af[i] = *(const short8*)&sA[buf][(w * 64 + i * 16 + col) * 32 + quad * 8];
        #pragma unroll
        for (int j = 0; j < 4; ++j) {
            ba[j] = *(const short8*)&sBa[buf][(j * 16 + col) * 32 + quad * 8];
            bg[j] = *(const short8*)&sBg[buf][(j * 16 + col) * 32 + quad * 8];
        }
        #pragma unroll
        for (int i = 0; i < 4; ++i)
            #pragma unroll
            for (int j = 0; j < 4; ++j) {
                acc_a[i][j] = __builtin_amdgcn_mfma_f32_16x16x32_bf16(af[i], ba[j], acc_a[i][j], 0, 0, 0);
                acc_g[i][j] = __builtin_amdgcn_mfma_f32_16x16x32_bf16(af[i], bg[j], acc_g[i][j], 0, 0, 0);
            }
        if (kc + 32 < 512) CVTW1(buf ^ 1);
    }
#undef LOADA1
#undef STAGEB1
#undef CVTW1

    #pragma unroll
    for (int j = 0; j < 4; ++j) {
        float bia = b1[n0 + j * 16 + col];
        float big = b1[512 + n0 + j * 16 + col];
        #pragma unroll
        for (int i = 0; i < 4; ++i) {
            #pragma unroll
            for (int r = 0; r < 4; ++r) {
                int row = q0 + w * 64 + i * 16 + quad * 4 + r;
                float a = acc_a[i][j][r] + bia;
                float g = acc_g[i][j][r] + big;
                y[((size_t)row << 9) + n0 + j * 16 + col] = f2bf(a * sigmoidf_(g));
            }
        }
    }
}

// ---- K2: depthwise conv utterance path + swish -> zb; also emits new_cache ----
__global__ __launch_bounds__(256) void k2_dw_utt(
    const ushort* __restrict__ y, const ushort* __restrict__ xc,
    const float* __restrict__ wd, const float* __restrict__ bd,
    ushort* __restrict__ z, float* __restrict__ out)
{
    __shared__ __attribute__((aligned(16))) ushort sy[64 * 97]; // [dl][p]
    __shared__ float sw[64 * 31];
    const int tid = threadIdx.x;
    const int u0 = blockIdx.x * 64;
    const int d0 = blockIdx.y * 64;
    const int b  = blockIdx.z;

    for (int idx = tid; idx < 94 * 8; idx += 256) {
        int r  = idx >> 3;   // pad-local 0..93
        int c8 = idx & 7;
        int p  = u0 + r;
        int dg = d0 + c8 * 8;
        const ushort* src = (p < CS) ? xc + (((size_t)(p * 16 + b)) << 9) + dg
                                     : y  + (((size_t)((482 + p) * 16 + b)) << 9) + dg;
        ushort tmp[8];
        *(int4*)tmp = *(const int4*)src;
        #pragma unroll
        for (int j = 0; j < 8; ++j) sy[(c8 * 8 + j) * 97 + r] = tmp[j];
    }
    for (int idx = tid; idx < 64 * 31; idx += 256) {
        int d = idx / 31, k = idx - d * 31;
        sw[d * 31 + k] = wd[(size_t)(d0 + d) * KS + k];
    }
    __syncthreads();

    const int dl   = tid & 63;
    const int useg = (tid >> 6) * 16;
    float win[46];
    #pragma unroll
    for (int p = 0; p < 46; ++p) win[p] = bf2f(sy[dl * 97 + useg + p]);
    float bias = bd[d0 + dl];
    float acc[16];
    #pragma unroll
    for (int i = 0; i < 16; ++i) acc[i] = bias;
    for (int k = 0; k < 31; ++k) {
        float w = sw[dl * 31 + k];
        #pragma unroll
        for (int i = 0; i < 16; ++i) acc[i] = fmaf(w, win[k + i], acc[i]);
    }
    #pragma unroll
    for (int i = 0; i < 16; ++i) {
        float v = acc[i];
        v = v * sigmoidf_(v - 1.0f);
        int u = u0 + useg + i;
        z[(((size_t)((R_LEN + u) * 16 + b)) << 9) + d0 + dl] = f2bf(v);
    }
    // new_cache: y frames t=2530..2559 = pad p=2048..2077 -> r=64..93 in block u0=1984
    if (blockIdx.x == 31) {
        for (int idx = tid; idx < 64 * 30; idx += 256) {
            int dl2 = idx & 63, j = idx >> 6;
            out[(size_t)20971520 + ((size_t)b * D_CH + d0 + dl2) * CS + j] = bf2f(sy[dl2 * 97 + 64 + j]);
        }
    }
}

// ---- K2rc: right-context chunked depthwise conv + swish -> zb ----
__global__ __launch_bounds__(256) void k2_dw_rc(
    const ushort* __restrict__ y, const float* __restrict__ wd, const float* __restrict__ bd,
    ushort* __restrict__ z)
{
    __shared__ __attribute__((aligned(16))) ushort sy[38 * 256]; // [frame][d_local]
    const int tid = threadIdx.x;
    const int i  = blockIdx.x;           // chunk 0..63
    const int b  = blockIdx.y;
    const int dbase = blockIdx.z * 256;

    for (int idx = tid; idx < 38 * 32; idx += 256) {
        int r  = idx >> 5;   // frame 0..37
        int c8 = idx & 31;
        int t = (r < CS) ? (R_LEN + 32 * i + 2 + r) : (8 * i + (r - CS));
        *(int4*)&sy[r * 256 + c8 * 8] =
            *(const int4*)(y + (((size_t)(t * 16 + b)) << 9) + dbase + c8 * 8);
    }
    __syncthreads();

    const int dd = dbase + tid;
    float wr[31];
    #pragma unroll
    for (int k = 0; k < 31; ++k) wr[k] = wd[(size_t)dd * KS + k];
    float bias = bd[dd];
    #pragma unroll
    for (int j = 0; j < 8; ++j) {
        float acc = bias;
        #pragma unroll
        for (int k = 0; k < 31; ++k) acc = fmaf(wr[k], bf2f(sy[(j + k) * 256 + tid]), acc);
        float v = acc * sigmoidf_(acc - 1.0f);
        z[(((size_t)((i * 8 + j) * 16 + b)) << 9) + dd] = f2bf(v);
    }
}

// ---- K3: dbuf MFMA GEMM (zb 40960x512 @ w2b^T) + bias -> final outputs fp32 ----
__global__ __launch_bounds__(256) void k3_mfma(
    const ushort* __restrict__ zb, const ushort* __restrict__ w2b,
    const float* __restrict__ b2, float* __restrict__ out)
{
    __shared__ __attribute__((aligned(16))) ushort sA[2][256 * 32];
    __shared__ __attribute__((aligned(16))) ushort sB[2][64 * 32];
    const int tid = threadIdx.x;
    const int w = tid >> 6, lane = tid & 63;
    const int f = blockIdx.x;
    const int xcd = f & 7, nn = (f >> 3) & 7, qh = f >> 6;
    const int q0 = (qh * 8 + xcd) * 256;
    const int n0 = nn * 64;
    const int col = lane & 15, quad = lane >> 4;

    floatx4 acc[4][4];
    #pragma unroll
    for (int i = 0; i < 4; ++i)
        #pragma unroll
        for (int j = 0; j < 4; ++j) acc[i][j] = 0.f;

    const int sBs = w * 64 + lane;
    const int sBr = sBs >> 2, sBh = sBs & 3;

#define STAGE3(kc, buf) do { \
        _Pragma("unroll") \
        for (int jj = 0; jj < 4; ++jj) { \
            int s = (w * 4 + jj) * 64 + lane; \
            gld16(zb + (((size_t)(q0 + (s >> 2))) << 9) + (kc) + (s & 3) * 8, \
                  &sA[buf][(w * 4 + jj) * 512]); \
        } \
        gld16(w2b + (((size_t)(n0 + sBr)) << 9) + (kc) + sBh * 8, &sB[buf][w * 512]); \
    } while (0)

    STAGE3(0, 0);
    #pragma unroll
    for (int kc = 0; kc < 512; kc += 32) {
        const int buf = (kc >> 5) & 1;
        __syncthreads();
        if (kc + 32 < 512) STAGE3(kc + 32, buf ^ 1);

        short8 af[4], bf[4];
        #pragma unroll
        for (int i = 0; i < 4; ++i)
            af[i] = *(const short8*)&sA[buf][(w * 64 + i * 16 + col) * 32 + quad * 8];
        #pragma unroll
        for (int j = 0; j < 4; ++j)
            bf[j] = *(const short8*)&sB[buf][(j * 16 + col) * 32 + quad * 8];
        #pragma unroll
        for (int i = 0; i < 4; ++i)
            #pragma unroll
            for (int j = 0; j < 4; ++j)
                acc[i][j] = __builtin_amdgcn_mfma_f32_16x16x32_bf16(af[i], bf[j], acc[i][j], 0, 0, 0);
    }
#undef STAGE3

    #pragma unroll
    for (int j = 0; j < 4; ++j) {
        float bb = b2[n0 + j * 16 + col];
        #pragma unroll
        for (int i = 0; i < 4; ++i) {
            #pragma unroll
            for (int r = 0; r < 4; ++r) {
                int q = q0 + w * 64 + i * 16 + quad * 4 + r;
                float v = acc[i][j][r] + bb;
                size_t off = (q < 8192) ? (size_t)16777216 + ((size_t)q << 9)
                                        : ((size_t)(q - 8192) << 9);
                out[off + n0 + j * 16 + col] = v;
            }
        }
    }
}

extern "C" void kernel_launch(void* const* d_in, const int* in_sizes, int n_in,
                              void* d_out, int out_size, void* d_ws, size_t ws_size,
                              hipStream_t stream)
{
    const float* utt   = (const float*)d_in[0];
    const float* rc    = (const float*)d_in[1];
    const float* cache = (const float*)d_in[2];
    const float* w1    = (const float*)d_in[3];
    const float* b1    = (const float*)d_in[4];
    const float* wd    = (const float*)d_in[5];
    const float* bd    = (const float*)d_in[6];
    const float* w2    = (const float*)d_in[7];
    const float* b2    = (const float*)d_in[8];
    float* out = (float*)d_out;

    ushort* y   = (ushort*)d_ws;                 // (T,B,D) bf16, rows q=t*16+b
    ushort* zb  = y   + (size_t)20971520;
    ushort* w1b = zb  + (size_t)20971520;
    ushort* w2b = w1b + (size_t)524288;
    ushort* xc  = w2b + (size_t)262144;          // (CS,B,D) bf16

    k_conv_small<<<dim3(1728),      256, 0, stream>>>(cache, w1, w2, w1b, w2b, xc);
    k1_mfma     <<<dim3(1280),      256, 0, stream>>>(utt, rc, w1b, b1, y);
    k2_dw_utt   <<<dim3(32, 8, 16), 256, 0, stream>>>(y, xc, wd, bd, zb, out);
    k2_dw_rc    <<<dim3(64, 16, 2), 256, 0, stream>>>(y, wd, bd, zb);
    k3_mfma     <<<dim3(1280),      256, 0, stream>>>(zb, w2b, b2, out);
}

// Round 6
// 351.414 us; speedup vs baseline: 1.1696x; 1.1696x over previous
//
#include <hip/hip_runtime.h>
#include <math.h>

#define B_SZ 16
#define D_CH 512
#define U_LEN 2048
#define R_LEN 512
#define T_LEN 2560
#define KS 31
#define CS 30

typedef __attribute__((ext_vector_type(8))) short short8;
typedef __attribute__((ext_vector_type(4))) float floatx4;

__device__ __forceinline__ float bf2f(ushort u) {
    unsigned v = (unsigned)u << 16;
    float f; __builtin_memcpy(&f, &v, 4); return f;
}
__device__ __forceinline__ ushort f2bf(float f) {
    unsigned v; __builtin_memcpy(&v, &f, 4);
    v += 0x7fff + ((v >> 16) & 1);
    return (ushort)(v >> 16);
}
__device__ __forceinline__ float sigmoidf_(float x) { return 1.0f / (1.0f + __expf(-x)); }

__device__ __forceinline__ void gld16(const void* g, void* l) {
    __builtin_amdgcn_global_load_lds((const __attribute__((address_space(1))) void*)g,
                                     (__attribute__((address_space(3))) void*)l, 16, 0, 0);
}

// ---- single conversion kernel: xb (T,B,D) bf16, weights bf16, cache -> (CS,B,D) bf16 ----
__global__ __launch_bounds__(256) void k_conv_all(
    const float* __restrict__ utt, const float* __restrict__ rc, const float* __restrict__ cache,
    const float* __restrict__ w1, const float* __restrict__ w2,
    ushort* __restrict__ xb, ushort* __restrict__ w1b, ushort* __restrict__ w2b,
    ushort* __restrict__ xc)
{
    int blk = blockIdx.x;
    if (blk < 5120) {
        size_t f4 = (size_t)blk * 1024 + threadIdx.x * 4;
        size_t o = f4 * 4;
        int q = (int)(o >> 9), d = (int)(o & 511);
        const float* src = (q < 8192) ? rc + ((size_t)q << 9) + d
                                      : utt + (((size_t)(q - 8192)) << 9) + d;
        ushort* dst = xb + o;
        #pragma unroll
        for (int i = 0; i < 4; ++i) {
            float4 v = ((const float4*)src)[i];
            ushort4 u4; u4.x = f2bf(v.x); u4.y = f2bf(v.y); u4.z = f2bf(v.z); u4.w = f2bf(v.w);
            ((ushort4*)dst)[i] = u4;
        }
    } else if (blk < 5312) {
        int t = (blk - 5120) * 1024 + threadIdx.x * 4;
        const float* src; ushort* dst;
        if (t < 131072) { src = w1; dst = w1b; }
        else            { t -= 131072; src = w2; dst = w2b; }
        #pragma unroll
        for (int i = 0; i < 4; ++i) {
            float4 v = ((const float4*)src)[t + i];
            ushort4 u4; u4.x = f2bf(v.x); u4.y = f2bf(v.y); u4.z = f2bf(v.z); u4.w = f2bf(v.w);
            ((ushort4*)dst)[t + i] = u4;
        }
    } else {
        int o = (blk - 5312) * 256 + threadIdx.x;
        int d = o & 511, p = o >> 13, b = (o >> 9) & 15;
        xc[o] = f2bf(cache[((size_t)b * D_CH + d) * CS + p]);
    }
}

// ---- K1: dbuf all-gld16 MFMA GEMM (xb @ w1b^T) + GLU -> y bf16, XCD-swizzled ----
// NO min-waves cap (R3: capping spills 128-VGPR accumulators -> 1.5GB scratch).
// Swizzle: q-tile = qh*8+xcd with xcd=f&7 pins all 8 n-sharers of an A-tile to
// one XCD (R5: FETCH 166->46MB).
__global__ __launch_bounds__(256) void k1_mfma(
    const ushort* __restrict__ xb, const ushort* __restrict__ w1b,
    const float* __restrict__ b1, ushort* __restrict__ y)
{
    __shared__ __attribute__((aligned(16))) ushort sA[2][256 * 32];
    __shared__ __attribute__((aligned(16))) ushort sBa[2][64 * 32];
    __shared__ __attribute__((aligned(16))) ushort sBg[2][64 * 32];
    const int tid = threadIdx.x;
    const int w = tid >> 6, lane = tid & 63;
    const int f = blockIdx.x;
    const int xcd = f & 7, nn = (f >> 3) & 7, qh = f >> 6;
    const int q0 = (qh * 8 + xcd) * 256;
    const int n0 = nn * 64;
    const int col = lane & 15, quad = lane >> 4;

    floatx4 acc_a[4][4], acc_g[4][4];
    #pragma unroll
    for (int i = 0; i < 4; ++i)
        #pragma unroll
        for (int j = 0; j < 4; ++j) { acc_a[i][j] = 0.f; acc_g[i][j] = 0.f; }

    const int sBs = w * 64 + lane;
    const int sBr = sBs >> 2, sBh = sBs & 3;

#define STAGE1(kc, buf) do { \
        _Pragma("unroll") \
        for (int jj = 0; jj < 4; ++jj) { \
            int s = (w * 4 + jj) * 64 + lane; \
            gld16(xb + (((size_t)(q0 + (s >> 2))) << 9) + (kc) + (s & 3) * 8, \
                  &sA[buf][(w * 4 + jj) * 512]); \
        } \
        gld16(w1b + (((size_t)(n0 + sBr)) << 9) + (kc) + sBh * 8, &sBa[buf][w * 512]); \
        gld16(w1b + (((size_t)(512 + n0 + sBr)) << 9) + (kc) + sBh * 8, &sBg[buf][w * 512]); \
    } while (0)

    STAGE1(0, 0);
    #pragma unroll
    for (int kc = 0; kc < 512; kc += 32) {
        const int buf = (kc >> 5) & 1;
        __syncthreads();
        if (kc + 32 < 512) STAGE1(kc + 32, buf ^ 1);

        short8 af[4], ba[4], bg[4];
        #pragma unroll
        for (int i = 0; i < 4; ++i)
            af[i] = *(const short8*)&sA[buf][(w * 64 + i * 16 + col) * 32 + quad * 8];
        #pragma unroll
        for (int j = 0; j < 4; ++j) {
            ba[j] = *(const short8*)&sBa[buf][(j * 16 + col) * 32 + quad * 8];
            bg[j] = *(const short8*)&sBg[buf][(j * 16 + col) * 32 + quad * 8];
        }
        #pragma unroll
        for (int i = 0; i < 4; ++i)
            #pragma unroll
            for (int j = 0; j < 4; ++j) {
                acc_a[i][j] = __builtin_amdgcn_mfma_f32_16x16x32_bf16(af[i], ba[j], acc_a[i][j], 0, 0, 0);
                acc_g[i][j] = __builtin_amdgcn_mfma_f32_16x16x32_bf16(af[i], bg[j], acc_g[i][j], 0, 0, 0);
            }
    }
#undef STAGE1

    #pragma unroll
    for (int j = 0; j < 4; ++j) {
        float bia = b1[n0 + j * 16 + col];
        float big = b1[512 + n0 + j * 16 + col];
        #pragma unroll
        for (int i = 0; i < 4; ++i) {
            #pragma unroll
            for (int r = 0; r < 4; ++r) {
                int row = q0 + w * 64 + i * 16 + quad * 4 + r;
                float a = acc_a[i][j][r] + bia;
                float g = acc_g[i][j][r] + big;
                y[((size_t)row << 9) + n0 + j * 16 + col] = f2bf(a * sigmoidf_(g));
            }
        }
    }
}

// ---- K2 fused: depthwise conv (utt path + rc path) + swish -> zb; emits new_cache ----
// LDS union ~20KB -> 7 blocks/CU.
__global__ __launch_bounds__(256) void k2_fused(
    const ushort* __restrict__ y, const ushort* __restrict__ xc,
    const float* __restrict__ wd, const float* __restrict__ bd,
    ushort* __restrict__ z, float* __restrict__ out)
{
    __shared__ __attribute__((aligned(16))) char smem[20352];
    const int tid = threadIdx.x;
    int g = blockIdx.x;

    if (g < 4096) {
        // ---- utterance path ----
        ushort* sy = (ushort*)smem;            // 64*97
        float*  sw = (float*)(smem + 12416);   // 64*31
        const int u0 = (g & 31) * 64;
        const int d0 = ((g >> 5) & 7) * 64;
        const int b  = g >> 8;

        for (int idx = tid; idx < 94 * 8; idx += 256) {
            int r  = idx >> 3;
            int c8 = idx & 7;
            int p  = u0 + r;
            int dg = d0 + c8 * 8;
            const ushort* src = (p < CS) ? xc + (((size_t)(p * 16 + b)) << 9) + dg
                                         : y  + (((size_t)((482 + p) * 16 + b)) << 9) + dg;
            ushort tmp[8];
            *(int4*)tmp = *(const int4*)src;
            #pragma unroll
            for (int j = 0; j < 8; ++j) sy[(c8 * 8 + j) * 97 + r] = tmp[j];
        }
        for (int idx = tid; idx < 64 * 31; idx += 256) {
            int d = idx / 31, k = idx - d * 31;
            sw[d * 31 + k] = wd[(size_t)(d0 + d) * KS + k];
        }
        __syncthreads();

        const int dl   = tid & 63;
        const int useg = (tid >> 6) * 16;
        float win[46];
        #pragma unroll
        for (int p = 0; p < 46; ++p) win[p] = bf2f(sy[dl * 97 + useg + p]);
        float bias = bd[d0 + dl];
        float acc[16];
        #pragma unroll
        for (int i = 0; i < 16; ++i) acc[i] = bias;
        for (int k = 0; k < 31; ++k) {
            float w = sw[dl * 31 + k];
            #pragma unroll
            for (int i = 0; i < 16; ++i) acc[i] = fmaf(w, win[k + i], acc[i]);
        }
        #pragma unroll
        for (int i = 0; i < 16; ++i) {
            float v = acc[i];
            v = v * sigmoidf_(v - 1.0f);
            int u = u0 + useg + i;
            z[(((size_t)((R_LEN + u) * 16 + b)) << 9) + d0 + dl] = f2bf(v);
        }
        // new_cache from staged frames p=2048..2077 (r=64..93 of block u0=1984)
        if ((g & 31) == 31) {
            for (int idx = tid; idx < 64 * 30; idx += 256) {
                int dl2 = idx & 63, j = idx >> 6;
                out[(size_t)20971520 + ((size_t)b * D_CH + d0 + dl2) * CS + j] = bf2f(sy[dl2 * 97 + 64 + j]);
            }
        }
    } else {
        // ---- right-context chunk path ----
        g -= 4096;
        ushort* sy = (ushort*)smem;            // 38*256
        const int i  = g & 63;
        const int b  = (g >> 6) & 15;
        const int dbase = (g >> 10) * 256;

        for (int idx = tid; idx < 38 * 32; idx += 256) {
            int r  = idx >> 5;
            int c8 = idx & 31;
            int t = (r < CS) ? (R_LEN + 32 * i + 2 + r) : (8 * i + (r - CS));
            *(int4*)&sy[r * 256 + c8 * 8] =
                *(const int4*)(y + (((size_t)(t * 16 + b)) << 9) + dbase + c8 * 8);
        }
        __syncthreads();

        const int dd = dbase + tid;
        float wr[31];
        #pragma unroll
        for (int k = 0; k < 31; ++k) wr[k] = wd[(size_t)dd * KS + k];
        float bias = bd[dd];
        #pragma unroll
        for (int j = 0; j < 8; ++j) {
            float acc = bias;
            #pragma unroll
            for (int k = 0; k < 31; ++k) acc = fmaf(wr[k], bf2f(sy[(j + k) * 256 + tid]), acc);
            float v = acc * sigmoidf_(acc - 1.0f);
            z[(((size_t)((i * 8 + j) * 16 + b)) << 9) + dd] = f2bf(v);
        }
    }
}

// ---- K3: dbuf all-gld16 MFMA GEMM (zb @ w2b^T) + bias -> final fp32, XCD-swizzled ----
__global__ __launch_bounds__(256) void k3_mfma(
    const ushort* __restrict__ zb, const ushort* __restrict__ w2b,
    const float* __restrict__ b2, float* __restrict__ out)
{
    __shared__ __attribute__((aligned(16))) ushort sA[2][256 * 32];
    __shared__ __attribute__((aligned(16))) ushort sB[2][64 * 32];
    const int tid = threadIdx.x;
    const int w = tid >> 6, lane = tid & 63;
    const int f = blockIdx.x;
    const int xcd = f & 7, nn = (f >> 3) & 7, qh = f >> 6;
    const int q0 = (qh * 8 + xcd) * 256;
    const int n0 = nn * 64;
    const int col = lane & 15, quad = lane >> 4;

    floatx4 acc[4][4];
    #pragma unroll
    for (int i = 0; i < 4; ++i)
        #pragma unroll
        for (int j = 0; j < 4; ++j) acc[i][j] = 0.f;

    const int sBs = w * 64 + lane;
    const int sBr = sBs >> 2, sBh = sBs & 3;

#define STAGE3(kc, buf) do { \
        _Pragma("unroll") \
        for (int jj = 0; jj < 4; ++jj) { \
            int s = (w * 4 + jj) * 64 + lane; \
            gld16(zb + (((size_t)(q0 + (s >> 2))) << 9) + (kc) + (s & 3) * 8, \
                  &sA[buf][(w * 4 + jj) * 512]); \
        } \
        gld16(w2b + (((size_t)(n0 + sBr)) << 9) + (kc) + sBh * 8, &sB[buf][w * 512]); \
    } while (0)

    STAGE3(0, 0);
    #pragma unroll
    for (int kc = 0; kc < 512; kc += 32) {
        const int buf = (kc >> 5) & 1;
        __syncthreads();
        if (kc + 32 < 512) STAGE3(kc + 32, buf ^ 1);

        short8 af[4], bf[4];
        #pragma unroll
        for (int i = 0; i < 4; ++i)
            af[i] = *(const short8*)&sA[buf][(w * 64 + i * 16 + col) * 32 + quad * 8];
        #pragma unroll
        for (int j = 0; j < 4; ++j)
            bf[j] = *(const short8*)&sB[buf][(j * 16 + col) * 32 + quad * 8];
        #pragma unroll
        for (int i = 0; i < 4; ++i)
            #pragma unroll
            for (int j = 0; j < 4; ++j)
                acc[i][j] = __builtin_amdgcn_mfma_f32_16x16x32_bf16(af[i], bf[j], acc[i][j], 0, 0, 0);
    }
#undef STAGE3

    #pragma unroll
    for (int j = 0; j < 4; ++j) {
        float bb = b2[n0 + j * 16 + col];
        #pragma unroll
        for (int i = 0; i < 4; ++i) {
            #pragma unroll
            for (int r = 0; r < 4; ++r) {
                int q = q0 + w * 64 + i * 16 + quad * 4 + r;
                float v = acc[i][j][r] + bb;
                size_t off = (q < 8192) ? (size_t)16777216 + ((size_t)q << 9)
                                        : ((size_t)(q - 8192) << 9);
                out[off + n0 + j * 16 + col] = v;
            }
        }
    }
}

extern "C" void kernel_launch(void* const* d_in, const int* in_sizes, int n_in,
                              void* d_out, int out_size, void* d_ws, size_t ws_size,
                              hipStream_t stream)
{
    const float* utt   = (const float*)d_in[0];
    const float* rc    = (const float*)d_in[1];
    const float* cache = (const float*)d_in[2];
    const float* w1    = (const float*)d_in[3];
    const float* b1    = (const float*)d_in[4];
    const float* wd    = (const float*)d_in[5];
    const float* bd    = (const float*)d_in[6];
    const float* w2    = (const float*)d_in[7];
    const float* b2    = (const float*)d_in[8];
    float* out = (float*)d_out;

    ushort* xb  = (ushort*)d_ws;                 // (T,B,D) bf16, rows q=t*16+b
    ushort* y   = xb  + (size_t)20971520;
    ushort* zb  = y   + (size_t)20971520;
    ushort* w1b = zb  + (size_t)20971520;
    ushort* w2b = w1b + (size_t)524288;
    ushort* xc  = w2b + (size_t)262144;          // (CS,B,D) bf16

    k_conv_all<<<dim3(6272), 256, 0, stream>>>(utt, rc, cache, w1, w2, xb, w1b, w2b, xc);
    k1_mfma   <<<dim3(1280), 256, 0, stream>>>(xb, w1b, b1, y);
    k2_fused  <<<dim3(6144), 256, 0, stream>>>(y, xc, wd, bd, zb, out);
    k3_mfma   <<<dim3(1280), 256, 0, stream>>>(zb, w2b, b2, out);
}